// Round 9
// baseline (96.299 us; speedup 1.0000x reference)
//
#include <hip/hip_runtime.h>
#include <hip/hip_bf16.h>
#include <stdint.h>

#define T_SEQ 4096

typedef float  f32x4   __attribute__((ext_vector_type(4)));
typedef float  f32x16  __attribute__((ext_vector_type(16)));
typedef short  bf16x8  __attribute__((ext_vector_type(8)));
typedef unsigned int u32x4 __attribute__((ext_vector_type(4)));

typedef const __attribute__((address_space(1))) uint32_t* gptr_t;
typedef __attribute__((address_space(3))) uint32_t* lptr_t;

__device__ __forceinline__ uint32_t f2bf1(float f) {
    uint32_t u = __float_as_uint(f);
    return (u + 0x7fffu + ((u >> 16) & 1u)) >> 16;   // RNE f32->bf16
}
__device__ __forceinline__ short f2bfs(float f) { return (short)f2bf1(f); }
__device__ __forceinline__ uint32_t cvtpk(float lo, float hi) {
    uint32_t r;
    asm("v_cvt_pk_bf16_f32 %0, %1, %2" : "=v"(r) : "v"(lo), "v"(hi));
    return r;
}

// ---------------------------------------------------------------------------
// Kernel 1: Q,K projections. Q pre-scaled by 0.125*log2(e) (softmax uses 2^x).
// Layout: [bh=b*2+h][t][64] bf16.
// ---------------------------------------------------------------------------
__global__ __launch_bounds__(256) void qk_proj(
    const float* __restrict__ x,
    const float* __restrict__ Wq1, const float* __restrict__ Wk1,
    const float* __restrict__ Wq2, const float* __restrict__ Wk2,
    short* __restrict__ Q, short* __restrict__ K)
{
    int idx = blockIdx.x * 256 + threadIdx.x;
    int d = idx & 63;
    int t = (idx >> 6) & (T_SEQ - 1);
    int b = idx >> 18;
    const float* xp = x + (size_t)(b * T_SEQ + t) * 6;
    float x0 = xp[0], x1 = xp[1], x2 = xp[2];
    float x3 = xp[3], x4 = xp[4], x5 = xp[5];
    const float QS = 0.125f * 1.44269504088896340736f;
    float q1 = (x0 * Wq1[d] + x1 * Wq1[64 + d] + x2 * Wq1[128 + d]) * QS;
    float k1 =  x0 * Wk1[d] + x1 * Wk1[64 + d] + x2 * Wk1[128 + d];
    float q2 = (x3 * Wq2[d] + x4 * Wq2[64 + d] + x5 * Wq2[128 + d]) * QS;
    float k2 =  x3 * Wk2[d] + x4 * Wk2[64 + d] + x5 * Wk2[128 + d];
    size_t base1 = ((size_t)(b * 2 + 0) * T_SEQ + t) * 64 + d;
    size_t base2 = ((size_t)(b * 2 + 1) * T_SEQ + t) * 64 + d;
    Q[base1] = f2bfs(q1);  Q[base2] = f2bfs(q2);
    K[base1] = f2bfs(k1);  K[base2] = f2bfs(k2);
}

// ---------------------------------------------------------------------------
// Kernel 2: V projection written TRANSPOSED: Vt[bh][d][t] bf16. (R0 layout)
// ---------------------------------------------------------------------------
__global__ __launch_bounds__(256) void v_proj_t(
    const float* __restrict__ x,
    const float* __restrict__ Wv1, const float* __restrict__ Wv2,
    short* __restrict__ Vt)
{
    int bh = blockIdx.x >> 6;
    int tt = blockIdx.x & 63;
    int head = bh & 1, b = bh >> 1;
    int t  = tt * 64 + (threadIdx.x & 63);
    int dg = threadIdx.x >> 6;
    const float* Wv = head ? Wv2 : Wv1;
    const float* xp = x + (size_t)(b * T_SEQ + t) * 6 + head * 3;
    float x0 = xp[0], x1 = xp[1], x2 = xp[2];
    size_t base = (size_t)bh * 64 * T_SEQ + t;
    #pragma unroll
    for (int k = 0; k < 16; ++k) {
        int d = dg * 16 + k;
        float v = x0 * Wv[d] + x1 * Wv[64 + d] + x2 * Wv[128 + d];
        Vt[base + (size_t)d * T_SEQ] = f2bfs(v);
    }
}

// ---------------------------------------------------------------------------
// Kernel 3: causal flash attention, FOLD-SHARED waves + KV-PARITY split.
//   R9 = R0's per-wave math x R8's kv-split parallelism:
//   - Block = 2 waves, pair of ADJACENT tiles E=2m (t0=64m), O=2m+1 (t0+32):
//     equal extents (m+1 chunks). Wave W = kv-half, computes BOTH tiles with
//     SHARED kf/vf fragments (R0's fold): 8 ds_reads serve 2 tile-units --
//     half of R8's LDS-read pipe work; addressing/loop VALU shared too.
//     (R8 post-mortem: time now tracks per-CU VALU+LDS pipe work, so cut it.)
//   - Block (m, p) processes chunks c = p, p+2, ... < m+1 (nb <= 32 bodies,
//     R8's critical path), emits UNNORMALIZED (acc, l): p=0 -> Hf+L0,
//     p=1 -> P1+L1 (additive static-max softmax). out_proj combines.
//   - No clamps/ghosts: staged kv0 <= 64m, +63 <= 4095 always.
//   - Regs ~160 unified (R0 measured 96 VGPR + 64 AGPR) -> (128,3);
//     LDS 32KB -> 5 blocks/CU = 10 waves/CU (~R8 residency, 2x the math/wave).
//   - FP accumulation order identical to R8 -> identical numerics.
// ---------------------------------------------------------------------------
__global__ __launch_bounds__(128, 3) void attn(
    const short* __restrict__ Q, const short* __restrict__ K,
    const short* __restrict__ Vt, float* __restrict__ Hf,
    float* __restrict__ P1, float* __restrict__ L0, float* __restrict__ L1)
{
    __shared__ __align__(16) char smem[32768];  // dbuf 2 x (K 8K + V 8K)

    int id = blockIdx.x;                 // 2048
    int xcd = id & 7, rest = id >> 3;    // rest 0..255
    int bh = xcd * 2 + (rest & 1);       // 2 bh per XCD (L2 locality)
    int rem = rest >> 1;                 // 0..127
    int m  = 63 - (rem >> 1);            // pair index, LONGEST FIRST
    int p  = rem & 1;                    // kv-parity half
    int tid = threadIdx.x;
    int W = tid >> 6;                    // wave = kv-half
    int lane = tid & 63;
    int ql = lane & 31, h = lane >> 5;
    int t0E = 64 * m, t0O = t0E + 32;
    int qE = t0E + ql, qO = t0O + ql;
    int nb = (m + 2 - p) >> 1;           // my chunk count: ceil((m+1-p)/2)
    int head = bh & 1, bb = bh >> 1;

    size_t kvbase = (size_t)bh * (T_SEQ * 64);

    // Q fragments for both tiles (B-operand): lane holds Q[q][ks*16+h*8+j]
    bf16x8 qfE[4], qfO[4];
    #pragma unroll
    for (int ks = 0; ks < 4; ++ks) {
        qfE[ks] = *(const bf16x8*)(Q + kvbase + (size_t)qE * 64 + ks * 16 + h * 8);
        qfO[ks] = *(const bf16x8*)(Q + kvbase + (size_t)qO * 64 + ks * 16 + h * 8);
    }

    // staging constants (128 threads): row16 = tid>>3 (0..15), slot = tid&7,
    // pre-swizzled source column; LDS dest linear (swizzle applied on read)
    int row16 = tid >> 3;
    int scol = ((tid & 7) ^ (row16 & 7)) * 8;
    const short* ksrc = K  + kvbase + (size_t)row16 * 64 + scol;
    const short* vsrc = Vt + kvbase + (size_t)row16 * T_SEQ + scol;

    f32x16 accE0, accE1, accO0, accO1;
    #pragma unroll
    for (int r = 0; r < 16; ++r) { accE0[r]=0.f; accE1[r]=0.f; accO0[r]=0.f; accO1[r]=0.f; }
    float lE = 0.f, lO = 0.f;
    int swz = (ql & 7) << 4;

#define STAGE(nb_, kvv)                                                         \
    _Pragma("unroll")                                                           \
    for (int z = 0; z < 4; ++z) {                                               \
        __builtin_amdgcn_global_load_lds(                                       \
            (gptr_t)(ksrc + (size_t)((kvv) + z * 16) * 64),                     \
            (lptr_t)((nb_) + z * 2048 + W * 1024), 16, 0, 0);                   \
        __builtin_amdgcn_global_load_lds(                                       \
            (gptr_t)(vsrc + (size_t)(z * 16) * T_SEQ + (kvv)),                  \
            (lptr_t)((nb_) + 8192 + z * 2048 + W * 1024), 16, 0, 0);            \
    }

#define QK_SM(qfX, qX, lX, pf0, pf1)                                            \
        {                                                                       \
            f32x16 Sv;                                                          \
            _Pragma("unroll") for (int r = 0; r < 16; ++r) Sv[r] = 0.f;         \
            Sv = __builtin_amdgcn_mfma_f32_32x32x16_bf16(kf0, qfX[0], Sv,0,0,0);\
            Sv = __builtin_amdgcn_mfma_f32_32x32x16_bf16(kf1, qfX[1], Sv,0,0,0);\
            Sv = __builtin_amdgcn_mfma_f32_32x32x16_bf16(kf2, qfX[2], Sv,0,0,0);\
            Sv = __builtin_amdgcn_mfma_f32_32x32x16_bf16(kf3, qfX[3], Sv,0,0,0);\
            bool needmask = (kv0 + 32 * W + 31 > (qX) - ql);  /* max_kv>t0X */  \
            uint32_t pw[8];                                                     \
            float l0 = 0.f, l1 = 0.f;                                           \
            _Pragma("unroll") for (int e = 0; e < 8; ++e) {                     \
                float p0 = __builtin_amdgcn_exp2f(Sv[2 * e]);                   \
                float p1 = __builtin_amdgcn_exp2f(Sv[2 * e + 1]);               \
                if (needmask) {                                                 \
                    int kv = kv0 + 32 * W + 4 * h + 2 * (e & 1) + 8 * (e >> 1); \
                    p0 = (kv     <= (qX)) ? p0 : 0.f;                           \
                    p1 = (kv + 1 <= (qX)) ? p1 : 0.f;                           \
                }                                                               \
                l0 += p0; l1 += p1;                                             \
                pw[e] = cvtpk(p0, p1);                                          \
            }                                                                   \
            lX += l0 + l1;                                                      \
            {                                                                   \
                uint32_t a0 = pw[0], b0 = pw[2], a1 = pw[1], b1 = pw[3];        \
                asm("v_permlane32_swap_b32 %0, %1" : "+v"(a0), "+v"(b0));       \
                asm("v_permlane32_swap_b32 %0, %1" : "+v"(a1), "+v"(b1));       \
                u32x4 fr = {a0, a1, b0, b1};                                    \
                pf0 = __builtin_bit_cast(bf16x8, fr);                           \
                uint32_t c0 = pw[4], d0 = pw[6], c1 = pw[5], d1 = pw[7];        \
                asm("v_permlane32_swap_b32 %0, %1" : "+v"(c0), "+v"(d0));       \
                asm("v_permlane32_swap_b32 %0, %1" : "+v"(c1), "+v"(d1));       \
                u32x4 fr1 = {c0, c1, d0, d1};                                   \
                pf1 = __builtin_bit_cast(bf16x8, fr1);                          \
            }                                                                   \
        }

#define BODY(jj)                                                                \
    {                                                                           \
        const int kv0 = 64 * (p + 2 * (jj));                                    \
        if ((jj) + 1 < nb) { char* nb_ = smem + (((jj) + 1) & 1) * 16384; STAGE(nb_, kv0 + 128); } \
        const char* ldsK = smem + ((jj) & 1) * 16384;                           \
        const char* ldsV = ldsK + 8192;                                         \
        bool actE = (kv0 + 32 * W <= t0E + 31);                                 \
        bool actO = (kv0 + 32 * W <= t0O + 31);                                 \
        const char* krow = ldsK + (32 * W + ql) * 128;                          \
        bf16x8 kf0 = *(const bf16x8*)(krow + ((0 * 32 + h * 16) ^ swz));        \
        bf16x8 kf1 = *(const bf16x8*)(krow + ((1 * 32 + h * 16) ^ swz));        \
        bf16x8 kf2 = *(const bf16x8*)(krow + ((2 * 32 + h * 16) ^ swz));        \
        bf16x8 kf3 = *(const bf16x8*)(krow + ((3 * 32 + h * 16) ^ swz));        \
        bf16x8 pfE0, pfE1, pfO0, pfO1;                                          \
        __builtin_amdgcn_s_setprio(1);                                          \
        if (actO) QK_SM(qfO, qO, lO, pfO0, pfO1)                                \
        if (actE) QK_SM(qfE, qE, lE, pfE0, pfE1)                                \
        int cb0 = (2 * W + 0) * 32 + h * 16;                                    \
        int cb1 = (2 * W + 1) * 32 + h * 16;                                    \
        bf16x8 vf00 = *(const bf16x8*)(ldsV + ql * 128        + (cb0 ^ swz));   \
        bf16x8 vf01 = *(const bf16x8*)(ldsV + ql * 128        + (cb1 ^ swz));   \
        bf16x8 vf10 = *(const bf16x8*)(ldsV + (32 + ql) * 128 + (cb0 ^ swz));   \
        bf16x8 vf11 = *(const bf16x8*)(ldsV + (32 + ql) * 128 + (cb1 ^ swz));   \
        if (actO) {                                                             \
            accO0 = __builtin_amdgcn_mfma_f32_32x32x16_bf16(vf00, pfO0, accO0, 0, 0, 0); \
            accO0 = __builtin_amdgcn_mfma_f32_32x32x16_bf16(vf01, pfO1, accO0, 0, 0, 0); \
            accO1 = __builtin_amdgcn_mfma_f32_32x32x16_bf16(vf10, pfO0, accO1, 0, 0, 0); \
            accO1 = __builtin_amdgcn_mfma_f32_32x32x16_bf16(vf11, pfO1, accO1, 0, 0, 0); \
        }                                                                       \
        if (actE) {                                                             \
            accE0 = __builtin_amdgcn_mfma_f32_32x32x16_bf16(vf00, pfE0, accE0, 0, 0, 0); \
            accE0 = __builtin_amdgcn_mfma_f32_32x32x16_bf16(vf01, pfE1, accE0, 0, 0, 0); \
            accE1 = __builtin_amdgcn_mfma_f32_32x32x16_bf16(vf10, pfE0, accE1, 0, 0, 0); \
            accE1 = __builtin_amdgcn_mfma_f32_32x32x16_bf16(vf11, pfE1, accE1, 0, 0, 0); \
        }                                                                       \
        __builtin_amdgcn_s_setprio(0);                                          \
        __syncthreads();                                                        \
    }

    if (nb > 0) STAGE(smem, 64 * p);     // prologue: first chunk -> buf 0
    __syncthreads();

    for (int j = 0; j < nb; ++j) BODY(j);
#undef BODY
#undef QK_SM
#undef STAGE

    // ---- combine: W0 publishes O / finalizes E; W1 publishes E / finalizes O.
    // Unnormalized partials to this parity's buffers (out_proj normalizes).
    lE += __shfl_xor(lE, 32);
    lO += __shfl_xor(lO, 32);
    float* RE = (float*)smem;            // [64][33] f32 for tile E
    float* RO = RE + 2112;               // [64][33] f32 for tile O
    if (W == 0) {                        // publish MY tile-O partial
        float* pb = RO + lane * 33;
        #pragma unroll
        for (int g = 0; g < 4; ++g) {
            *(f32x4*)(pb + 4 * g)      = f32x4{accO0[4*g+0], accO0[4*g+1], accO0[4*g+2], accO0[4*g+3]};
            *(f32x4*)(pb + 16 + 4 * g) = f32x4{accO1[4*g+0], accO1[4*g+1], accO1[4*g+2], accO1[4*g+3]};
        }
        pb[32] = lO;
    } else {                             // publish MY tile-E partial
        float* pb = RE + lane * 33;
        #pragma unroll
        for (int g = 0; g < 4; ++g) {
            *(f32x4*)(pb + 4 * g)      = f32x4{accE0[4*g+0], accE0[4*g+1], accE0[4*g+2], accE0[4*g+3]};
            *(f32x4*)(pb + 16 + 4 * g) = f32x4{accE1[4*g+0], accE1[4*g+1], accE1[4*g+2], accE1[4*g+3]};
        }
        pb[32] = lE;
    }
    __syncthreads();
    {
        float* Pdst = p ? P1 : Hf;
        float* Ldst = p ? L1 : L0;
        float* pb = (W ? RO : RE) + lane * 33;
        f32x16 a0 = W ? accO0 : accE0;
        f32x16 a1 = W ? accO1 : accE1;
        float lf = (W ? lO : lE) + pb[32];
        int t0 = W ? t0O : t0E;
        float* hp = Pdst + ((size_t)(bb * T_SEQ) + t0 + ql) * 128 + head * 64 + 4 * h;
        #pragma unroll
        for (int g2 = 0; g2 < 4; ++g2) {
            f32x4 o0 = *(f32x4*)(pb + g2 * 4);
            f32x4 o1 = *(f32x4*)(pb + 16 + g2 * 4);
            f32x4 s0 = { a0[g2*4+0]+o0[0], a0[g2*4+1]+o0[1],
                         a0[g2*4+2]+o0[2], a0[g2*4+3]+o0[3] };
            *(f32x4*)(hp + 8 * g2) = s0;               // d = 8*g2+4h+0..3
            f32x4 s1 = { a1[g2*4+0]+o1[0], a1[g2*4+1]+o1[1],
                         a1[g2*4+2]+o1[2], a1[g2*4+3]+o1[3] };
            *(f32x4*)(hp + 32 + 8 * g2) = s1;          // d = 32+8*g2+4h+0..3
        }
        if (h == 0)                       // one lane per q-row
            Ldst[(size_t)bh * T_SEQ + t0 + ql] = lf;
    }
}

// ---------------------------------------------------------------------------
// Kernel 4a: one-shot Wout -> Wt bf16, transposed + xor-swizzled for LDS.
// ---------------------------------------------------------------------------
__global__ __launch_bounds__(256) void prep_wt(
    const float* __restrict__ Wout, short* __restrict__ Wt)
{
    int tid = blockIdx.x * 256 + threadIdx.x;   // 16384
    int j = tid >> 7, k = tid & 127;
    float v = Wout[k * 128 + j];
    int slot = k >> 3;
    Wt[j * 128 + (((slot ^ (j & 7)) << 3) | (k & 7))] = f2bfs(v);
}

// ---------------------------------------------------------------------------
// Kernel 4b: out = ((P0+P1) * 1/(L0+L1)) @ Wout -> f32 (in place over P0).
// Row-block-diagonal: each wave reads only its own 16 rows before writing.
// Normalization folded into the bf16 fragment build (per-head rl).
// ---------------------------------------------------------------------------
__global__ __launch_bounds__(256) void out_proj(
    const float* P0, const float* __restrict__ P1,
    const float* __restrict__ L0, const float* __restrict__ L1,
    const short* __restrict__ Wt, float* out)
{
    __shared__ __align__(16) char lws[32768];
    int tid = threadIdx.x;
    int w = tid >> 6, lane = tid & 63, c = lane & 15, g = lane >> 4;
    int cs = c & 7;
    #pragma unroll
    for (int z = 0; z < 8; ++z)
        __builtin_amdgcn_global_load_lds((gptr_t)(Wt + z * 2048 + w * 512 + lane * 8),
                                         (lptr_t)(lws + z * 4096 + w * 1024), 16, 0, 0);
    __syncthreads();

    int row0 = blockIdx.x * 64 + w * 16;
    int r = row0 + c;
    int b = r >> 12, t = r & (T_SEQ - 1);
    float rl0 = 1.0f / (L0[(size_t)(b * 2 + 0) * T_SEQ + t] + L1[(size_t)(b * 2 + 0) * T_SEQ + t]);
    float rl1 = 1.0f / (L0[(size_t)(b * 2 + 1) * T_SEQ + t] + L1[(size_t)(b * 2 + 1) * T_SEQ + t]);

    bf16x8 af[4];
    const float* hp0 = P0 + (size_t)r * 128 + g * 8;
    const float* hp1 = P1 + (size_t)r * 128 + g * 8;
    #pragma unroll
    for (int kc = 0; kc < 4; ++kc) {
        float rl = (kc < 2) ? rl0 : rl1;          // d = kc*32+g*8+.. ; head = d>>6
        f32x4 x0 = *(const f32x4*)(hp0 + kc * 32);
        f32x4 x1 = *(const f32x4*)(hp0 + kc * 32 + 4);
        f32x4 y0 = *(const f32x4*)(hp1 + kc * 32);
        f32x4 y1 = *(const f32x4*)(hp1 + kc * 32 + 4);
        u32x4 wv = { cvtpk((x0[0]+y0[0])*rl, (x0[1]+y0[1])*rl),
                     cvtpk((x0[2]+y0[2])*rl, (x0[3]+y0[3])*rl),
                     cvtpk((x1[0]+y1[0])*rl, (x1[1]+y1[1])*rl),
                     cvtpk((x1[2]+y1[2])*rl, (x1[3]+y1[3])*rl) };
        af[kc] = __builtin_bit_cast(bf16x8, wv);
    }
    #pragma unroll
    for (int jt = 0; jt < 8; ++jt) {
        f32x4 accum = {0.f, 0.f, 0.f, 0.f};
        #pragma unroll
        for (int kc = 0; kc < 4; ++kc) {
            int row = jt * 16 + c;
            bf16x8 bfr = *(const bf16x8*)(lws + row * 256 + (((kc * 4 + g) ^ cs) << 4));
            accum = __builtin_amdgcn_mfma_f32_16x16x32_bf16(af[kc], bfr, accum, 0, 0, 0);
        }
        #pragma unroll
        for (int rr = 0; rr < 4; ++rr)
            out[(size_t)(row0 + g * 4 + rr) * 128 + jt * 16 + c] = accum[rr];
    }
}

// ---------------------------------------------------------------------------
extern "C" void kernel_launch(void* const* d_in, const int* in_sizes, int n_in,
                              void* d_out, int out_size, void* d_ws, size_t ws_size,
                              hipStream_t stream)
{
    (void)in_sizes; (void)n_in; (void)out_size; (void)ws_size;
    const float* x    = (const float*)d_in[0];
    const float* Wq1  = (const float*)d_in[1];
    const float* Wk1  = (const float*)d_in[2];
    const float* Wv1  = (const float*)d_in[3];
    const float* Wq2  = (const float*)d_in[4];
    const float* Wk2  = (const float*)d_in[5];
    const float* Wv2  = (const float*)d_in[6];
    const float* Wout = (const float*)d_in[7];
    float* out = (float*)d_out;

    char* ws = (char*)d_ws;
    short* Q  = (short*)(ws);                               // 8 MiB (dead after attn)
    short* K  = (short*)(ws + (size_t)8  * 1024 * 1024);    // 8 MiB
    short* Vt = (short*)(ws + (size_t)16 * 1024 * 1024);    // 8 MiB
    float* P1 = (float*)(ws + (size_t)24 * 1024 * 1024);    // 16 MiB partial
    float* L0 = (float*)(ws + (size_t)40 * 1024 * 1024);    // 256 KiB
    float* L1 = (float*)(ws + (size_t)40 * 1024 * 1024 + 262144);
    short* Wt = Q;                                          // reuse Q region
    float* Hf = out;                                        // P0 lives in d_out

    qk_proj <<<8192, 256, 0, stream>>>(x, Wq1, Wk1, Wq2, Wk2, Q, K);
    v_proj_t<<<1024, 256, 0, stream>>>(x, Wv1, Wv2, Vt);
    attn    <<<2048, 128, 0, stream>>>(Q, K, Vt, Hf, P1, L0, L1);
    prep_wt <<<  64, 256, 0, stream>>>(Wout, Wt);
    out_proj<<< 512, 256, 0, stream>>>(Hf, P1, L0, L1, Wt, out);
}